// Round 6
// baseline (97.129 us; speedup 1.0000x reference)
//
#include <hip/hip_runtime.h>

// Problem dims (fixed): B=8, n=128, d=512, h=1024
constexpr int Bn = 8, Nn = 128, Dd = 512, Hh = 1024;
constexpr int Ff = 2 * Dd;              // 1024
constexpr int KS = 16, KCH = Dd / KS;   // 16 K-splits x 32

// ws float offsets
constexpr int VOFF = 0;       // v[0..1024], v[Ff] = c
constexpr int CNT  = 1088;    // 32 int counters (one per (b,tile))
constexpr int AOFF = 2048;    // alpha partials [s][b][128]
constexpr int BOFF = 20480;   // beta partials  [s][b][128]
constexpr int POFF = 65536;   // tile partials [s][b][tile][64*64]

// ---------------------------------------------------------------------------
// Kernel 1: v[f] = W1[f,:].W2 ; v[Ff] = b1.W2 + b2 ; zero finalize counters.
// 257 blocks x 256 thr (1 wave per row) — high TLP for the 4 MB W1 read.
// ---------------------------------------------------------------------------
__global__ __launch_bounds__(256) void k_wv(const float* __restrict__ W1,
                                            const float* __restrict__ b1,
                                            const float* __restrict__ W2,
                                            const float* __restrict__ b2,
                                            float* __restrict__ ws) {
    const int wave = (int)((blockIdx.x * 256u + threadIdx.x) >> 6);
    const int lane = threadIdx.x & 63;

    if (blockIdx.x == 256 && threadIdx.x >= 64 && threadIdx.x < 96)
        ((int*)(ws + CNT))[threadIdx.x - 64] = 0;   // counters for k_bil

    const float* row;
    if (wave < Ff)       row = W1 + (size_t)wave * Hh;
    else if (wave == Ff) row = b1;
    else return;

    const float4* r4 = (const float4*)row;
    const float4* w4 = (const float4*)W2;
    float p = 0.f;
#pragma unroll
    for (int q = 0; q < Hh / 256; ++q) {
        float4 x = r4[lane + 64 * q], y = w4[lane + 64 * q];
        p = fmaf(x.x, y.x, p); p = fmaf(x.y, y.y, p);
        p = fmaf(x.z, y.z, p); p = fmaf(x.w, y.w, p);
    }
#pragma unroll
    for (int off = 32; off; off >>= 1) p += __shfl_down(p, off);
    if (lane == 0) ws[VOFF + wave] = (wave == Ff) ? (p + b2[0]) : p;
}

// ---------------------------------------------------------------------------
// Kernel 2: bilinear partials + last-block finalize.
// Grid (16 s, 4 tile, 8 b) = 512 blocks (2/CU), 256 thr, 64x64 tile,
// 4x4 micro (k-major LDS, conflict-free b128 reads).
// ---------------------------------------------------------------------------
__global__ __launch_bounds__(256) void k_bil(const float* __restrict__ A,
                                             const float* __restrict__ Bm,
                                             float* __restrict__ ws,
                                             float* __restrict__ out) {
    __shared__ float v1_s[KCH], v2_s[KCH];
    __shared__ float aw_t[KCH][64];   // k-major premultiplied a*v1
    __shared__ float b_t[KCH][64];    // k-major raw b
    __shared__ float apart[64], bpart[64];
    __shared__ float asum[64], bsum[64];
    __shared__ int lastflag;

    const int s = blockIdx.x, tile = blockIdx.y, b = blockIdx.z;
    const int it = tile >> 1, jt = tile & 1;
    const int t = threadIdx.x;
    const int K0 = s * KCH;

    if (t < KCH)            v1_s[t] = ws[VOFF + K0 + t];
    else if (t < 2 * KCH)   v2_s[t - KCH] = ws[VOFF + Dd + K0 + (t - KCH)];
    __syncthreads();

    // ---- staging: row = t>>2 (64 rows), q = t&3 (8 k's each). One aligned
    //      128B line per row per block: perfect coalescing, no duplicate fetch.
    {
        const int row = t >> 2, q = t & 3, k0 = 8 * q;
        const float* arow = A  + ((size_t)(b * Nn + it * 64 + row)) * Dd + K0 + k0;
        const float* brow = Bm + ((size_t)(b * Nn + jt * 64 + row)) * Dd + K0 + k0;
        const float4 a0 = ((const float4*)arow)[0], a1 = ((const float4*)arow)[1];
        const float4 b0 = ((const float4*)brow)[0], b1v = ((const float4*)brow)[1];

        aw_t[k0 + 0][row] = a0.x * v1_s[k0 + 0];
        aw_t[k0 + 1][row] = a0.y * v1_s[k0 + 1];
        aw_t[k0 + 2][row] = a0.z * v1_s[k0 + 2];
        aw_t[k0 + 3][row] = a0.w * v1_s[k0 + 3];
        aw_t[k0 + 4][row] = a1.x * v1_s[k0 + 4];
        aw_t[k0 + 5][row] = a1.y * v1_s[k0 + 5];
        aw_t[k0 + 6][row] = a1.z * v1_s[k0 + 6];
        aw_t[k0 + 7][row] = a1.w * v1_s[k0 + 7];
        b_t[k0 + 0][row] = b0.x;  b_t[k0 + 1][row] = b0.y;
        b_t[k0 + 2][row] = b0.z;  b_t[k0 + 3][row] = b0.w;
        b_t[k0 + 4][row] = b1v.x; b_t[k0 + 5][row] = b1v.y;
        b_t[k0 + 6][row] = b1v.z; b_t[k0 + 7][row] = b1v.w;

        float al = a0.x * v2_s[k0 + 0] + a0.y * v2_s[k0 + 1]
                 + a0.z * v2_s[k0 + 2] + a0.w * v2_s[k0 + 3]
                 + a1.x * v2_s[k0 + 4] + a1.y * v2_s[k0 + 5]
                 + a1.z * v2_s[k0 + 6] + a1.w * v2_s[k0 + 7];
        float be = b0.x * v2_s[k0 + 0] + b0.y * v2_s[k0 + 1]
                 + b0.z * v2_s[k0 + 2] + b0.w * v2_s[k0 + 3]
                 + b1v.x * v2_s[k0 + 4] + b1v.y * v2_s[k0 + 5]
                 + b1v.z * v2_s[k0 + 6] + b1v.w * v2_s[k0 + 7];
        al += __shfl_xor(al, 1); al += __shfl_xor(al, 2);
        be += __shfl_xor(be, 1); be += __shfl_xor(be, 2);
        if (q == 0) { apart[row] = al; bpart[row] = be; }
    }
    __syncthreads();

    if (jt == 0 && t < 64)
        ws[AOFF + (s * Bn + b) * Nn + it * 64 + t] = apart[t];
    if (it == 0 && t >= 64 && t < 128)
        ws[BOFF + (s * Bn + b) * Nn + jt * 64 + (t - 64)] = bpart[t - 64];

    // ---- 4x4 micro-tile over 32 k's: 2 conflict-free b128 reads + 16 FMA per k
    const int tr = t >> 4, tc = t & 15;
    float4 acc0 = {0,0,0,0}, acc1 = {0,0,0,0}, acc2 = {0,0,0,0}, acc3 = {0,0,0,0};
#pragma unroll
    for (int k = 0; k < KCH; ++k) {
        const float4 av = *(const float4*)&aw_t[k][4 * tr];
        const float4 bv = *(const float4*)&b_t[k][4 * tc];
        acc0.x = fmaf(av.x, bv.x, acc0.x); acc0.y = fmaf(av.x, bv.y, acc0.y);
        acc0.z = fmaf(av.x, bv.z, acc0.z); acc0.w = fmaf(av.x, bv.w, acc0.w);
        acc1.x = fmaf(av.y, bv.x, acc1.x); acc1.y = fmaf(av.y, bv.y, acc1.y);
        acc1.z = fmaf(av.y, bv.z, acc1.z); acc1.w = fmaf(av.y, bv.w, acc1.w);
        acc2.x = fmaf(av.z, bv.x, acc2.x); acc2.y = fmaf(av.z, bv.y, acc2.y);
        acc2.z = fmaf(av.z, bv.z, acc2.z); acc2.w = fmaf(av.z, bv.w, acc2.w);
        acc3.x = fmaf(av.w, bv.x, acc3.x); acc3.y = fmaf(av.w, bv.y, acc3.y);
        acc3.z = fmaf(av.w, bv.z, acc3.z); acc3.w = fmaf(av.w, bv.w, acc3.w);
    }

    float* pb = ws + POFF + ((size_t)((s * Bn + b) * 4 + tile)) * 4096
                + (4 * tr) * 64 + 4 * tc;
    *(float4*)(pb +   0) = acc0;
    *(float4*)(pb +  64) = acc1;
    *(float4*)(pb + 128) = acc2;
    *(float4*)(pb + 192) = acc3;

    // ---- last block of each (b,tile) group finalizes (deterministic s-order)
    __threadfence();
    if (t == 0) {
        const int r = atomicAdd((int*)(ws + CNT) + (b * 4 + tile), 1);
        lastflag = (r == KS - 1);
    }
    __syncthreads();
    if (!lastflag) return;
    __threadfence();

    if (t < 64) {
        float v = 0.f;
#pragma unroll
        for (int ss = 0; ss < KS; ++ss)
            v += ws[AOFF + (ss * Bn + b) * Nn + it * 64 + t];
        asum[t] = v;
    } else if (t < 128) {
        const int j = t - 64;
        float v = 0.f;
#pragma unroll
        for (int ss = 0; ss < KS; ++ss)
            v += ws[BOFF + (ss * Bn + b) * Nn + jt * 64 + j];
        bsum[j] = v;
    }
    if (t == 0) ((int*)(ws + CNT))[b * 4 + tile] = 0;   // reset for next call
    __syncthreads();

    const float c = ws[VOFF + Ff];
#pragma unroll
    for (int e = 0; e < 4; ++e) {
        const int fi = t + 256 * e;          // float4 index in 64x64 tile
        const int r = fi >> 4, c4 = fi & 15;
        float4 o = {0,0,0,0};
#pragma unroll
        for (int ss = 0; ss < KS; ++ss) {
            const float4 p = *(const float4*)&ws[POFF +
                ((size_t)((ss * Bn + b) * 4 + tile)) * 4096 + 4 * fi];
            o.x += p.x; o.y += p.y; o.z += p.z; o.w += p.w;
        }
        const float av_ = asum[r];
        o.x += av_ - bsum[4 * c4 + 0] + c;
        o.y += av_ - bsum[4 * c4 + 1] + c;
        o.z += av_ - bsum[4 * c4 + 2] + c;
        o.w += av_ - bsum[4 * c4 + 3] + c;
        *(float4*)&out[((size_t)(b * Nn + it * 64 + r)) * Nn + jt * 64 + 4 * c4] = o;
    }
}

extern "C" void kernel_launch(void* const* d_in, const int* in_sizes, int n_in,
                              void* d_out, int out_size, void* d_ws, size_t ws_size,
                              hipStream_t stream) {
    const float* a  = (const float*)d_in[0];
    const float* b  = (const float*)d_in[1];
    const float* W1 = (const float*)d_in[2];
    const float* b1 = (const float*)d_in[3];
    const float* W2 = (const float*)d_in[4];
    const float* b2 = (const float*)d_in[5];
    float* out = (float*)d_out;
    float* ws  = (float*)d_ws;

    k_wv<<<257, 256, 0, stream>>>(W1, b1, W2, b2, ws);

    dim3 g2(KS, 4, Bn);   // (16, 4, 8) = 512 blocks = 2/CU
    k_bil<<<g2, 256, 0, stream>>>(a, b, ws, out);
}

// Round 7
// 21.829 us; speedup vs baseline: 4.4496x; 4.4496x over previous
//
#include <hip/hip_runtime.h>

// Problem dims (fixed): B=8, n=128, d=512, h=1024
constexpr int Bn = 8, Nn = 128, Dd = 512, Hh = 1024;
constexpr int Ff = 2 * Dd;              // 1024
constexpr int KS = 16, KCH = Dd / KS;   // 16 K-splits x 32

// ws float offsets
constexpr int VOFF = 0;       // v[0..1024], v[Ff] = c
constexpr int AOFF = 2048;    // alpha partials [s][b][128]   (16*8*128)
constexpr int BOFF = 20480;   // beta partials  [s][b][128]
constexpr int POFF = 65536;   // tile partials [s][b][tile][64*64]

// ---------------------------------------------------------------------------
// Kernel 1: v[f] = W1[f,:].W2 ; v[Ff] = b1.W2 + b2.
// 257 blocks x 256 thr, one wave per row (high TLP for the 4 MB W1 read).
// ---------------------------------------------------------------------------
__global__ __launch_bounds__(256) void k_wv(const float* __restrict__ W1,
                                            const float* __restrict__ b1,
                                            const float* __restrict__ W2,
                                            const float* __restrict__ b2,
                                            float* __restrict__ ws) {
    const int wave = (int)((blockIdx.x * 256u + threadIdx.x) >> 6);
    const int lane = threadIdx.x & 63;
    const float* row;
    if (wave < Ff)       row = W1 + (size_t)wave * Hh;
    else if (wave == Ff) row = b1;
    else return;

    const float4* r4 = (const float4*)row;
    const float4* w4 = (const float4*)W2;
    float p = 0.f;
#pragma unroll
    for (int q = 0; q < Hh / 256; ++q) {
        float4 x = r4[lane + 64 * q], y = w4[lane + 64 * q];
        p = fmaf(x.x, y.x, p); p = fmaf(x.y, y.y, p);
        p = fmaf(x.z, y.z, p); p = fmaf(x.w, y.w, p);
    }
#pragma unroll
    for (int off = 32; off; off >>= 1) p += __shfl_down(p, off);
    if (lane == 0) ws[VOFF + wave] = (wave == Ff) ? (p + b2[0]) : p;
}

// ---------------------------------------------------------------------------
// Kernel 2: bilinear partials. Grid (16 s, 4 tile, 8 b) = 512 blocks = 2/CU
// so co-resident blocks overlap each other's staging latency.
// 64x64 tile, KCH=32, 4x4 micro, k-major LDS (conflict-free).
// ---------------------------------------------------------------------------
__global__ __launch_bounds__(256) void k_bil(const float* __restrict__ A,
                                             const float* __restrict__ Bm,
                                             float* __restrict__ ws) {
    __shared__ float v1_s[KCH], v2_s[KCH];
    __shared__ float aw_t[KCH][64];   // k-major premultiplied a*v1
    __shared__ float b_t[KCH][64];    // k-major raw b
    __shared__ float apart[64], bpart[64];

    const int s = blockIdx.x, tile = blockIdx.y, b = blockIdx.z;
    const int it = tile >> 1, jt = tile & 1;
    const int t = threadIdx.x;
    const int K0 = s * KCH;

    if (t < KCH)            v1_s[t] = ws[VOFF + K0 + t];
    else if (t < 2 * KCH)   v2_s[t - KCH] = ws[VOFF + Dd + K0 + (t - KCH)];
    __syncthreads();

    // ---- staging: 64 rows x 4 threads/row, 2 float4 each (64B contiguous
    //      per 4-lane group). Transpose to k-major; alpha/beta inline.
    {
        const int row = t >> 2, q4 = t & 3;
        const float4* arow = (const float4*)(A  + ((size_t)(b * Nn + it * 64 + row)) * Dd + K0);
        const float4* brow = (const float4*)(Bm + ((size_t)(b * Nn + jt * 64 + row)) * Dd + K0);
        const float4 a0 = arow[q4], a1 = arow[q4 + 4];
        const float4 b0 = brow[q4], b1v = brow[q4 + 4];
        const int ka = 4 * q4, kb = 4 * q4 + 16;

        aw_t[ka + 0][row] = a0.x * v1_s[ka + 0];
        aw_t[ka + 1][row] = a0.y * v1_s[ka + 1];
        aw_t[ka + 2][row] = a0.z * v1_s[ka + 2];
        aw_t[ka + 3][row] = a0.w * v1_s[ka + 3];
        aw_t[kb + 0][row] = a1.x * v1_s[kb + 0];
        aw_t[kb + 1][row] = a1.y * v1_s[kb + 1];
        aw_t[kb + 2][row] = a1.z * v1_s[kb + 2];
        aw_t[kb + 3][row] = a1.w * v1_s[kb + 3];
        b_t[ka + 0][row] = b0.x;  b_t[ka + 1][row] = b0.y;
        b_t[ka + 2][row] = b0.z;  b_t[ka + 3][row] = b0.w;
        b_t[kb + 0][row] = b1v.x; b_t[kb + 1][row] = b1v.y;
        b_t[kb + 2][row] = b1v.z; b_t[kb + 3][row] = b1v.w;

        float al = a0.x * v2_s[ka + 0] + a0.y * v2_s[ka + 1]
                 + a0.z * v2_s[ka + 2] + a0.w * v2_s[ka + 3]
                 + a1.x * v2_s[kb + 0] + a1.y * v2_s[kb + 1]
                 + a1.z * v2_s[kb + 2] + a1.w * v2_s[kb + 3];
        float be = b0.x * v2_s[ka + 0] + b0.y * v2_s[ka + 1]
                 + b0.z * v2_s[ka + 2] + b0.w * v2_s[ka + 3]
                 + b1v.x * v2_s[kb + 0] + b1v.y * v2_s[kb + 1]
                 + b1v.z * v2_s[kb + 2] + b1v.w * v2_s[kb + 3];
        al += __shfl_xor(al, 1); al += __shfl_xor(al, 2);
        be += __shfl_xor(be, 1); be += __shfl_xor(be, 2);
        if (q4 == 0) { apart[row] = al; bpart[row] = be; }
    }
    __syncthreads();

    if (jt == 0 && t < 64)
        ws[AOFF + (s * Bn + b) * Nn + it * 64 + t] = apart[t];
    if (it == 0 && t >= 64 && t < 128)
        ws[BOFF + (s * Bn + b) * Nn + jt * 64 + (t - 64)] = bpart[t - 64];

    // ---- 4x4 micro over 32 k's: 2 conflict-free ds_read_b128 + 16 FMA per k
    const int tr = t >> 4, tc = t & 15;
    float4 acc0 = {0,0,0,0}, acc1 = {0,0,0,0}, acc2 = {0,0,0,0}, acc3 = {0,0,0,0};
#pragma unroll
    for (int k = 0; k < KCH; ++k) {
        const float4 av = *(const float4*)&aw_t[k][4 * tr];
        const float4 bv = *(const float4*)&b_t[k][4 * tc];
        acc0.x = fmaf(av.x, bv.x, acc0.x); acc0.y = fmaf(av.x, bv.y, acc0.y);
        acc0.z = fmaf(av.x, bv.z, acc0.z); acc0.w = fmaf(av.x, bv.w, acc0.w);
        acc1.x = fmaf(av.y, bv.x, acc1.x); acc1.y = fmaf(av.y, bv.y, acc1.y);
        acc1.z = fmaf(av.y, bv.z, acc1.z); acc1.w = fmaf(av.y, bv.w, acc1.w);
        acc2.x = fmaf(av.z, bv.x, acc2.x); acc2.y = fmaf(av.z, bv.y, acc2.y);
        acc2.z = fmaf(av.z, bv.z, acc2.z); acc2.w = fmaf(av.z, bv.w, acc2.w);
        acc3.x = fmaf(av.w, bv.x, acc3.x); acc3.y = fmaf(av.w, bv.y, acc3.y);
        acc3.z = fmaf(av.w, bv.z, acc3.z); acc3.w = fmaf(av.w, bv.w, acc3.w);
    }

    float* pb = ws + POFF + ((size_t)((s * Bn + b) * 4 + tile)) * 4096
                + (4 * tr) * 64 + 4 * tc;
    *(float4*)(pb +   0) = acc0;
    *(float4*)(pb +  64) = acc1;
    *(float4*)(pb + 128) = acc2;
    *(float4*)(pb + 192) = acc3;
}

// ---------------------------------------------------------------------------
// Kernel 3: out[b,i,j] = sum_s part + alpha[b,i] - beta[b,j] + c
// 128 blocks x 256 threads, one float4 of output per thread.
// ---------------------------------------------------------------------------
__global__ __launch_bounds__(256) void k_red(const float* __restrict__ ws,
                                             float* __restrict__ out) {
    const int idx = blockIdx.x * 256 + threadIdx.x;  // float4 idx, 0..32767
    const int j4 = idx & 31;
    const int i  = (idx >> 5) & 127;
    const int b  = idx >> 12;
    const int tile = (i >> 6) * 2 + (j4 >> 4);
    const int off  = (i & 63) * 64 + (j4 & 15) * 4;

    float4 o = {0.f, 0.f, 0.f, 0.f};
    float asum = 0.f;
    float bx = 0.f, by = 0.f, bz = 0.f, bw = 0.f;
#pragma unroll
    for (int s = 0; s < KS; ++s) {
        const float4 p = *(const float4*)&ws[POFF +
            ((size_t)((s * Bn + b) * 4 + tile)) * 4096 + off];
        o.x += p.x; o.y += p.y; o.z += p.z; o.w += p.w;
        asum += ws[AOFF + (s * Bn + b) * Nn + i];
        const float4 bb = *(const float4*)&ws[BOFF + (s * Bn + b) * Nn + 4 * j4];
        bx += bb.x; by += bb.y; bz += bb.z; bw += bb.w;
    }
    const float c = ws[VOFF + Ff];
    o.x += asum - bx + c;
    o.y += asum - by + c;
    o.z += asum - bz + c;
    o.w += asum - bw + c;
    *(float4*)&out[((size_t)(b * Nn + i)) * Nn + 4 * j4] = o;
}

extern "C" void kernel_launch(void* const* d_in, const int* in_sizes, int n_in,
                              void* d_out, int out_size, void* d_ws, size_t ws_size,
                              hipStream_t stream) {
    const float* a  = (const float*)d_in[0];
    const float* b  = (const float*)d_in[1];
    const float* W1 = (const float*)d_in[2];
    const float* b1 = (const float*)d_in[3];
    const float* W2 = (const float*)d_in[4];
    const float* b2 = (const float*)d_in[5];
    float* out = (float*)d_out;
    float* ws  = (float*)d_ws;

    k_wv<<<257, 256, 0, stream>>>(W1, b1, W2, b2, ws);

    dim3 g2(KS, 4, Bn);   // (16, 4, 8) = 512 blocks = 2/CU
    k_bil<<<g2, 256, 0, stream>>>(a, b, ws);

    k_red<<<128, 256, 0, stream>>>(ws, out);
}

// Round 8
// 14.220 us; speedup vs baseline: 6.8302x; 1.5350x over previous
//
#include <hip/hip_runtime.h>

// Problem dims (fixed): B=8, n=128, d=512, h=1024
constexpr int Bn = 8, Nn = 128, Dd = 512, Hh = 1024;
constexpr int Ff = 2 * Dd;   // 1024

using bf16x8 = __attribute__((ext_vector_type(8))) short;
using f32x4  = __attribute__((ext_vector_type(4))) float;

// float -> bf16 payload, round-to-nearest-even
static __device__ inline unsigned short f2bf(float x) {
    unsigned u = __float_as_uint(x);
    u += 0x7FFF + ((u >> 16) & 1);
    return (unsigned short)(u >> 16);
}
static __device__ inline unsigned pk2(float lo, float hi) {
    return (unsigned)f2bf(lo) | ((unsigned)f2bf(hi) << 16);
}

// ---------------------------------------------------------------------------
// Kernel 1: v[f] = W1[f,:].W2 ; v[Ff] = b1.W2 + b2.  (257 blocks, 1 wave/row)
// ---------------------------------------------------------------------------
__global__ __launch_bounds__(256) void k_wv(const float* __restrict__ W1,
                                            const float* __restrict__ b1,
                                            const float* __restrict__ W2,
                                            const float* __restrict__ b2,
                                            float* __restrict__ ws) {
    const int wave = (int)((blockIdx.x * 256u + threadIdx.x) >> 6);
    const int lane = threadIdx.x & 63;
    const float* row;
    if (wave < Ff)       row = W1 + (size_t)wave * Hh;
    else if (wave == Ff) row = b1;
    else return;

    const float4* r4 = (const float4*)row;
    const float4* w4 = (const float4*)W2;
    float p = 0.f;
#pragma unroll
    for (int q = 0; q < Hh / 256; ++q) {
        float4 x = r4[lane + 64 * q], y = w4[lane + 64 * q];
        p = fmaf(x.x, y.x, p); p = fmaf(x.y, y.y, p);
        p = fmaf(x.z, y.z, p); p = fmaf(x.w, y.w, p);
    }
#pragma unroll
    for (int off = 32; off; off >>= 1) p += __shfl_down(p, off);
    if (lane == 0) ws[wave] = (wave == Ff) ? (p + b2[0]) : p;
}

// ---------------------------------------------------------------------------
// Kernel 2: full-K MFMA GEMM per 32x16 output tile, direct out. No partials.
// Grid (32 tiles, 8 batch) = 256 blocks x 256 thr.
// LDS tiles bf16, row stride 520 (1040 B: rows advance 4 banks -> <=2-way).
// Wave w covers K slice [128w,128w+128) with mfma_f32_16x16x32_bf16;
// 4-wave reduce through LDS; alpha/beta computed inline at staging.
// ---------------------------------------------------------------------------
constexpr int TI = 32, TJ = 16, LDK = Dd + 8;   // 520

__global__ __launch_bounds__(256) void k_gemm(const float* __restrict__ A,
                                              const float* __restrict__ Bm,
                                              const float* __restrict__ ws,
                                              float* __restrict__ out) {
    __shared__ unsigned short aw_s[TI][LDK];   // bf16 payloads of a*v1
    __shared__ unsigned short b_s[TJ][LDK];    // bf16 payloads of b
    __shared__ float red[4][TI * TJ];          // per-wave fp32 results
    __shared__ float alpha_s[TI], beta_s[TJ];

    const int tile = blockIdx.x, b = blockIdx.y;
    const int brow = (tile >> 3) * TI;          // 4 i-tiles
    const int bcol = (tile & 7) * TJ;           // 8 j-tiles
    const int t = threadIdx.x;

    const float* v1 = ws;
    const float* v2 = ws + Dd;

    // ---- stage A-tile: 32 rows x 8 thr/row; k = 4*(t&7) + 32*q (coalesced)
    {
        const int row = t >> 3, s = t & 7;
        const float* ar = A + ((size_t)(b * Nn + brow + row)) * Dd;
        float alp = 0.f;
#pragma unroll
        for (int q = 0; q < 16; ++q) {
            const int k = 4 * s + 32 * q;
            const float4 a4 = *(const float4*)(ar + k);
            const float4 w1 = *(const float4*)(v1 + k);
            const float4 w2 = *(const float4*)(v2 + k);
            alp = fmaf(a4.x, w2.x, alp); alp = fmaf(a4.y, w2.y, alp);
            alp = fmaf(a4.z, w2.z, alp); alp = fmaf(a4.w, w2.w, alp);
            unsigned lo = pk2(a4.x * w1.x, a4.y * w1.y);
            unsigned hi = pk2(a4.z * w1.z, a4.w * w1.w);
            *(uint2*)&aw_s[row][k] = make_uint2(lo, hi);
        }
        alp += __shfl_xor(alp, 1);
        alp += __shfl_xor(alp, 2);
        alp += __shfl_xor(alp, 4);
        if (s == 0) alpha_s[row] = alp;
    }
    // ---- stage B-tile: 16 rows x 16 thr/row; k = 4*(t&15) + 64*q
    {
        const int row = t >> 4, s = t & 15;
        const float* br = Bm + ((size_t)(b * Nn + bcol + row)) * Dd;
        float bep = 0.f;
#pragma unroll
        for (int q = 0; q < 8; ++q) {
            const int k = 4 * s + 64 * q;
            const float4 b4 = *(const float4*)(br + k);
            const float4 w2 = *(const float4*)(v2 + k);
            bep = fmaf(b4.x, w2.x, bep); bep = fmaf(b4.y, w2.y, bep);
            bep = fmaf(b4.z, w2.z, bep); bep = fmaf(b4.w, w2.w, bep);
            unsigned lo = pk2(b4.x, b4.y);
            unsigned hi = pk2(b4.z, b4.w);
            *(uint2*)&b_s[row][k] = make_uint2(lo, hi);
        }
        bep += __shfl_xor(bep, 1);
        bep += __shfl_xor(bep, 2);
        bep += __shfl_xor(bep, 4);
        bep += __shfl_xor(bep, 8);
        if (s == 0) beta_s[row] = bep;
    }
    __syncthreads();

    // ---- MFMA: wave w takes K in [128w, 128w+128)
    {
        const int wave = t >> 6, lane = t & 63;
        const int r16 = lane & 15, ksel = lane >> 4;
        f32x4 acc0 = {0.f, 0.f, 0.f, 0.f};
        f32x4 acc1 = {0.f, 0.f, 0.f, 0.f};
#pragma unroll
        for (int ks = 0; ks < 4; ++ks) {
            const int k = 128 * wave + 32 * ks + 8 * ksel;
            const bf16x8 af0 = *(const bf16x8*)&aw_s[r16][k];
            const bf16x8 af1 = *(const bf16x8*)&aw_s[16 + r16][k];
            const bf16x8 bf  = *(const bf16x8*)&b_s[r16][k];
            acc0 = __builtin_amdgcn_mfma_f32_16x16x32_bf16(af0, bf, acc0, 0, 0, 0);
            acc1 = __builtin_amdgcn_mfma_f32_16x16x32_bf16(af1, bf, acc1, 0, 0, 0);
        }
        // C layout: col = lane&15, row = 4*(lane>>4) + reg
        float* rw = red[wave];
#pragma unroll
        for (int r = 0; r < 4; ++r) {
            rw[(4 * ksel + r) * TJ + r16]        = acc0[r];
            rw[(16 + 4 * ksel + r) * TJ + r16]   = acc1[r];
        }
    }
    __syncthreads();

    // ---- epilogue: sum 4 waves + alpha - beta + c, direct to out
    const float c = ws[Ff];
#pragma unroll
    for (int e = t; e < TI * TJ; e += 256) {
        const int row = e >> 4, col = e & 15;
        const float sum = red[0][e] + red[1][e] + red[2][e] + red[3][e];
        out[((size_t)(b * Nn + brow + row)) * Nn + bcol + col] =
            sum + alpha_s[row] - beta_s[col] + c;
    }
}

extern "C" void kernel_launch(void* const* d_in, const int* in_sizes, int n_in,
                              void* d_out, int out_size, void* d_ws, size_t ws_size,
                              hipStream_t stream) {
    const float* a  = (const float*)d_in[0];
    const float* b  = (const float*)d_in[1];
    const float* W1 = (const float*)d_in[2];
    const float* b1 = (const float*)d_in[3];
    const float* W2 = (const float*)d_in[4];
    const float* b2 = (const float*)d_in[5];
    float* out = (float*)d_out;
    float* ws  = (float*)d_ws;   // v[0..1024]

    k_wv<<<257, 256, 0, stream>>>(W1, b1, W2, b2, ws);

    dim3 g2(32, Bn);   // (tiles, batch) = 256 blocks
    k_gemm<<<g2, 256, 0, stream>>>(a, b, ws, out);
}

// Round 9
// 14.108 us; speedup vs baseline: 6.8849x; 1.0080x over previous
//
#include <hip/hip_runtime.h>
#include <hip/hip_bf16.h>

// Problem dims (fixed): B=8, n=128, d=512, h=1024
constexpr int Bn = 8, Nn = 128, Dd = 512, Hh = 1024;
constexpr int Ff = 2 * Dd;   // 1024

using bf16x8 = __attribute__((ext_vector_type(8))) short;
using f32x4  = __attribute__((ext_vector_type(4))) float;

// pack two floats to bf16x2 payload via native converts (RNE)
static __device__ inline unsigned pk2(float lo, float hi) {
    __hip_bfloat16 l = __float2bfloat16(lo);
    __hip_bfloat16 h = __float2bfloat16(hi);
    return (unsigned)*(unsigned short*)&l | ((unsigned)*(unsigned short*)&h << 16);
}

// ---------------------------------------------------------------------------
// Kernel 1: v[f] = W1[f,:].W2 ; v[Ff] = b1.W2 + b2.  (257 blocks, 1 wave/row)
// ---------------------------------------------------------------------------
__global__ __launch_bounds__(256) void k_wv(const float* __restrict__ W1,
                                            const float* __restrict__ b1,
                                            const float* __restrict__ W2,
                                            const float* __restrict__ b2,
                                            float* __restrict__ ws) {
    const int wave = (int)((blockIdx.x * 256u + threadIdx.x) >> 6);
    const int lane = threadIdx.x & 63;
    const float* row;
    if (wave < Ff)       row = W1 + (size_t)wave * Hh;
    else if (wave == Ff) row = b1;
    else return;

    const float4* r4 = (const float4*)row;
    const float4* w4 = (const float4*)W2;
    float p = 0.f;
#pragma unroll
    for (int q = 0; q < Hh / 256; ++q) {
        float4 x = r4[lane + 64 * q], y = w4[lane + 64 * q];
        p = fmaf(x.x, y.x, p); p = fmaf(x.y, y.y, p);
        p = fmaf(x.z, y.z, p); p = fmaf(x.w, y.w, p);
    }
#pragma unroll
    for (int off = 32; off; off >>= 1) p += __shfl_down(p, off);
    if (lane == 0) ws[wave] = (wave == Ff) ? (p + b2[0]) : p;
}

// ---------------------------------------------------------------------------
// Kernel 2: full-K MFMA GEMM per 32x16 output tile, direct out.
// Grid (32 tiles, 8 batch) = 256 blocks x 256 thr.
// A-tile staged RAW bf16 (32 rows); B-tile staged premultiplied by v1
// (16 rows — half the mul work of scaling A). alpha from raw fp32 a,
// beta from raw fp32 b, computed inline at staging.
// LDS row stride 520 (1040 B) -> <=2-way bank aliasing on b128 reads (free).
// Wave w covers K slice [128w,128w+128) with mfma_f32_16x16x32_bf16;
// 4-wave fp32 reduce through LDS.
// ---------------------------------------------------------------------------
constexpr int TI = 32, TJ = 16, LDK = Dd + 8;   // 520

__global__ __launch_bounds__(256) void k_gemm(const float* __restrict__ A,
                                              const float* __restrict__ Bm,
                                              const float* __restrict__ ws,
                                              float* __restrict__ out) {
    __shared__ __align__(16) unsigned short a_s[TI][LDK];    // raw a (bf16)
    __shared__ __align__(16) unsigned short bw_s[TJ][LDK];   // b*v1 (bf16)
    __shared__ float red[4][TI * TJ];
    __shared__ float alpha_s[TI], beta_s[TJ];

    const int tile = blockIdx.x, b = blockIdx.y;
    const int brow = (tile >> 3) * TI;          // 4 i-tiles
    const int bcol = (tile & 7) * TJ;           // 8 j-tiles
    const int t = threadIdx.x;

    const float* v1 = ws;
    const float* v2 = ws + Dd;

    // ---- stage A-tile raw: 32 rows x 8 thr/row; k = 4*(t&7) + 32*q
    {
        const int row = t >> 3, s = t & 7;
        const float* ar = A + ((size_t)(b * Nn + brow + row)) * Dd;
        float alp = 0.f;
#pragma unroll
        for (int q = 0; q < 16; ++q) {
            const int k = 4 * s + 32 * q;
            const float4 a4 = *(const float4*)(ar + k);
            const float4 w2 = *(const float4*)(v2 + k);
            alp = fmaf(a4.x, w2.x, alp); alp = fmaf(a4.y, w2.y, alp);
            alp = fmaf(a4.z, w2.z, alp); alp = fmaf(a4.w, w2.w, alp);
            *(uint2*)&a_s[row][k] = make_uint2(pk2(a4.x, a4.y), pk2(a4.z, a4.w));
        }
        alp += __shfl_xor(alp, 1);
        alp += __shfl_xor(alp, 2);
        alp += __shfl_xor(alp, 4);
        if (s == 0) alpha_s[row] = alp;
    }
    // ---- stage B-tile premultiplied: 16 rows x 16 thr/row; k = 4*(t&15)+64*q
    {
        const int row = t >> 4, s = t & 15;
        const float* br = Bm + ((size_t)(b * Nn + bcol + row)) * Dd;
        float bep = 0.f;
#pragma unroll
        for (int q = 0; q < 8; ++q) {
            const int k = 4 * s + 64 * q;
            const float4 b4 = *(const float4*)(br + k);
            const float4 w1 = *(const float4*)(v1 + k);
            const float4 w2 = *(const float4*)(v2 + k);
            bep = fmaf(b4.x, w2.x, bep); bep = fmaf(b4.y, w2.y, bep);
            bep = fmaf(b4.z, w2.z, bep); bep = fmaf(b4.w, w2.w, bep);
            *(uint2*)&bw_s[row][k] =
                make_uint2(pk2(b4.x * w1.x, b4.y * w1.y),
                           pk2(b4.z * w1.z, b4.w * w1.w));
        }
        bep += __shfl_xor(bep, 1);
        bep += __shfl_xor(bep, 2);
        bep += __shfl_xor(bep, 4);
        bep += __shfl_xor(bep, 8);
        if (s == 0) beta_s[row] = bep;
    }
    __syncthreads();

    // ---- MFMA: wave w takes K in [128w, 128w+128)
    {
        const int wave = t >> 6, lane = t & 63;
        const int r16 = lane & 15, ksel = lane >> 4;
        f32x4 acc0 = {0.f, 0.f, 0.f, 0.f};
        f32x4 acc1 = {0.f, 0.f, 0.f, 0.f};
#pragma unroll
        for (int ks = 0; ks < 4; ++ks) {
            const int k = 128 * wave + 32 * ks + 8 * ksel;
            const bf16x8 af0 = *(const bf16x8*)&a_s[r16][k];
            const bf16x8 af1 = *(const bf16x8*)&a_s[16 + r16][k];
            const bf16x8 bf  = *(const bf16x8*)&bw_s[r16][k];
            acc0 = __builtin_amdgcn_mfma_f32_16x16x32_bf16(af0, bf, acc0, 0, 0, 0);
            acc1 = __builtin_amdgcn_mfma_f32_16x16x32_bf16(af1, bf, acc1, 0, 0, 0);
        }
        // C layout: col = lane&15, row = 4*(lane>>4) + reg
        float* rw = red[wave];
#pragma unroll
        for (int r = 0; r < 4; ++r) {
            rw[(4 * ksel + r) * TJ + r16]      = acc0[r];
            rw[(16 + 4 * ksel + r) * TJ + r16] = acc1[r];
        }
    }
    __syncthreads();

    // ---- epilogue: sum 4 waves + alpha - beta + c, direct to out
    const float c = ws[Ff];
#pragma unroll
    for (int e = t; e < TI * TJ; e += 256) {
        const int row = e >> 4, col = e & 15;
        const float sum = red[0][e] + red[1][e] + red[2][e] + red[3][e];
        out[((size_t)(b * Nn + brow + row)) * Nn + bcol + col] =
            sum + alpha_s[row] - beta_s[col] + c;
    }
}

extern "C" void kernel_launch(void* const* d_in, const int* in_sizes, int n_in,
                              void* d_out, int out_size, void* d_ws, size_t ws_size,
                              hipStream_t stream) {
    const float* a  = (const float*)d_in[0];
    const float* b  = (const float*)d_in[1];
    const float* W1 = (const float*)d_in[2];
    const float* b1 = (const float*)d_in[3];
    const float* W2 = (const float*)d_in[4];
    const float* b2 = (const float*)d_in[5];
    float* out = (float*)d_out;
    float* ws  = (float*)d_ws;   // v[0..1024]

    k_wv<<<257, 256, 0, stream>>>(W1, b1, W2, b2, ws);

    dim3 g2(32, Bn);   // (tiles, batch) = 256 blocks
    k_gemm<<<g2, 256, 0, stream>>>(a, b, ws, out);
}